// Round 9
// baseline (356.135 us; speedup 1.0000x reference)
//
#include <hip/hip_runtime.h>
#include <hip/hip_bf16.h>

// TrajectoryDecoder: B=8192 LSTM, T=128, H=128, CTX=256, IN_DIM=132.
// R9: co-residency attempt #3 — BB=16, grid=512, 2 blocks/CU, with the
// register budget enforced on the UNIFIED file via amdgpu_waves_per_eu(4)
// (R7's failure theory: VGPR_Count=128 excluded AGPR accumulators -> total
// >128 -> 3 waves/SIMD -> single block). Diet: gate_static -> LDS f32x4
// [g][tid] (C-operand seed), WoF -> LDS (wave-7 reads 4xb128/step),
// streamed A-frags. Steady live set ~115 regs.
// Also: 7-trans/element update (common-denominator c), exp2 with log2e
// pre-folded into per-gate weight scaling {L,L,2L,L}; single fmax(cv,-15)
// guard (i/f/g/o exp2 args provably < 60, no overflow path).

#define HDIM 128
#define CTX_DIM 256
#define T_FRAMES 128
#define BB 16     // batch rows per block
#define STR 136   // h row stride (elements); 272B rows keep 16B alignment

typedef __bf16 bf16x8 __attribute__((ext_vector_type(8)));
typedef float  f32x4  __attribute__((ext_vector_type(4)));

union frag_u {
  bf16x8 v;
  unsigned short s[8];
  uint4 u4;
};

#if __has_builtin(__builtin_amdgcn_exp2f)
#define EXP2(x) __builtin_amdgcn_exp2f(x)
#else
#define EXP2(x) __expf((x) * 0.6931471805599453f)
#endif
#define RCP(x) __builtin_amdgcn_rcpf(x)

__device__ __forceinline__ unsigned short f2bf(float x) {
  unsigned u = __builtin_bit_cast(unsigned, x);
  u += 0x7FFFu + ((u >> 16) & 1u);          // RNE to bf16
  return (unsigned short)(u >> 16);
}
__device__ __forceinline__ float bf2f(unsigned short h) {
  unsigned u = ((unsigned)h) << 16;
  return __builtin_bit_cast(float, u);
}
template<int CTRL>
__device__ __forceinline__ float dpp_mov(float x) {
  return __builtin_bit_cast(float,
    __builtin_amdgcn_mov_dpp(__builtin_bit_cast(int, x), CTRL, 0xF, 0xF, true));
}
// sum over the 16-lane row group (setup-only)
__device__ __forceinline__ float row_reduce16(float v) {
  v += dpp_mov<0xB1>(v);
  v += dpp_mov<0x4E>(v);
  v += dpp_mov<0x124>(v);
  v += dpp_mov<0x128>(v);
  return v;
}

#define MFMA(a, b, c) __builtin_amdgcn_mfma_f32_16x16x32_bf16((a), (b), (c), 0, 0, 0)

__attribute__((amdgpu_waves_per_eu(4)))
__global__ __launch_bounds__(512) void traj_lstm(
    const float* __restrict__ ctx, const float* __restrict__ enc,
    const float* __restrict__ ball,
    const float* __restrict__ Wh, const float* __restrict__ bh,
    const float* __restrict__ Wc, const float* __restrict__ bc,
    const float* __restrict__ W_ih, const float* __restrict__ W_hh,
    const float* __restrict__ b_ih, const float* __restrict__ b_hh,
    const float* __restrict__ Wo, const float* __restrict__ bo,
    float* __restrict__ outp)
{
  __shared__ __align__(16) __bf16 sh_h[2][BB * STR];          // 8.7 KB
  __shared__ __align__(16) unsigned short sh_sA[BB * 264];    // 8.4 KB setup hi
  __shared__ __align__(16) unsigned short sh_sB[BB * 264];    // 8.4 KB setup lo
  __shared__ __align__(16) f32x4 sh_g4[4][512];               // 32 KB gate_static
  __shared__ __align__(16) uint4 sh_wof[4][64];               // 4 KB Wo frags (wave 7)
  __shared__ float sh_pw0[8][BB * 2];     // setup pred partials (1 KB)
  __shared__ float sh_p0[BB * 2];         // virtual pred_{-1}

  const int tid  = threadIdx.x;
  const int w    = tid >> 6;
  const int l    = tid & 63;
  const int q    = l >> 4;
  const int c16  = l & 15;
  const int colH = w * 16 + c16;
  const int rbase = blockIdx.x * BB;

  const float Lc = 1.4426950408889634f;          // log2(e)
  const float bo0 = bo[0], bo1 = bo[1];
  const float wo0 = Wo[colH], wo1 = Wo[HDIM + colH];

  // raw feedback weights + per-gate exp2 prescale
  float wp0[4], wp1[4];
  #pragma unroll
  for (int g = 0; g < 4; ++g) {
    wp0[g] = W_ih[(size_t)(g * HDIM + colH) * 132 + 0];
    wp1[g] = W_ih[(size_t)(g * HDIM + colH) * 132 + 1];
  }
  const float SG[4] = {Lc, Lc, 2.f * Lc, Lc};    // i, f, g, o gate scales

  // ---- persistent W_eff fragments: SG[g]*(W_hh + wp0*Wo0 + wp1*Wo1) ----
  frag_u Wf[4][4];                  // [gate][ktile]  (64 VGPRs, loop-resident)
  #pragma unroll
  for (int kt = 0; kt < 4; ++kt) {
    const float* w0p = Wo + kt * 32 + q * 8;
    const float* w1p = Wo + HDIM + kt * 32 + q * 8;
    float4 a0 = *(const float4*)w0p, a1 = *(const float4*)(w0p + 4);
    float4 b0 = *(const float4*)w1p, b1 = *(const float4*)(w1p + 4);
    float wo0v[8] = {a0.x, a0.y, a0.z, a0.w, a1.x, a1.y, a1.z, a1.w};
    float wo1v[8] = {b0.x, b0.y, b0.z, b0.w, b1.x, b1.y, b1.z, b1.w};
    #pragma unroll
    for (int g = 0; g < 4; ++g) {
      const float* wr = W_hh + (size_t)(g * HDIM + colH) * HDIM + kt * 32 + q * 8;
      float4 f0 = *(const float4*)wr;
      float4 f1 = *(const float4*)(wr + 4);
      float ff[8] = {f0.x, f0.y, f0.z, f0.w, f1.x, f1.y, f1.z, f1.w};
      #pragma unroll
      for (int j = 0; j < 8; ++j)
        Wf[g][kt].s[j] = f2bf(SG[g] * (ff[j] + wp0[g] * wo0v[j] + wp1[g] * wo1v[j]));
    }
  }

  // ---- Wo B-fragments -> LDS (read back by wave 7 in-loop) ----
  if (w == 7) {
    #pragma unroll
    for (int kt = 0; kt < 4; ++kt) {
      frag_u WoF;
      #pragma unroll
      for (int j = 0; j < 8; ++j) {
        float x = (c16 < 2) ? Wo[c16 * HDIM + kt * 32 + q * 8 + j] : 0.f;
        WoF.s[j] = f2bf(x);
      }
      sh_wof[kt][l] = WoF.u4;
    }
  }

  // ---- stage context rows (hi/lo bf16, stride 264) ----
  for (int e = tid; e < BB * 256; e += 512) {
    int row = e >> 8, col = e & 255;
    float x = ctx[(size_t)(rbase + row) * CTX_DIM + col];
    unsigned short hb = f2bf(x);
    sh_sA[row * 264 + col] = hb;
    sh_sB[row * 264 + col] = f2bf(x - bf2f(hb));
  }
  __syncthreads();

  // ---- h0/c0 = ctx @ Wh.T/Wc.T + bias (3-product split, K=256) ----
  float cst[4];
  {
    f32x4 aH = {0.f, 0.f, 0.f, 0.f}, aC = {0.f, 0.f, 0.f, 0.f};
    #pragma unroll
    for (int kt = 0; kt < 8; ++kt) {
      frag_u Ahi, Alo;
      Ahi.u4 = *(const uint4*)&sh_sA[c16 * 264 + kt * 32 + q * 8];
      Alo.u4 = *(const uint4*)&sh_sB[c16 * 264 + kt * 32 + q * 8];
      frag_u bhi, blo;
      {
        const float* wr = Wh + (size_t)colH * CTX_DIM + kt * 32 + q * 8;
        float4 f0 = *(const float4*)wr;
        float4 f1 = *(const float4*)(wr + 4);
        float ff[8] = {f0.x, f0.y, f0.z, f0.w, f1.x, f1.y, f1.z, f1.w};
        #pragma unroll
        for (int j = 0; j < 8; ++j) {
          unsigned short hb = f2bf(ff[j]);
          bhi.s[j] = hb;
          blo.s[j] = f2bf(ff[j] - bf2f(hb));
        }
      }
      aH = MFMA(Ahi.v, bhi.v, aH);
      aH = MFMA(Alo.v, bhi.v, aH);
      aH = MFMA(Ahi.v, blo.v, aH);
      {
        const float* wr = Wc + (size_t)colH * CTX_DIM + kt * 32 + q * 8;
        float4 f0 = *(const float4*)wr;
        float4 f1 = *(const float4*)(wr + 4);
        float ff[8] = {f0.x, f0.y, f0.z, f0.w, f1.x, f1.y, f1.z, f1.w};
        #pragma unroll
        for (int j = 0; j < 8; ++j) {
          unsigned short hb = f2bf(ff[j]);
          bhi.s[j] = hb;
          blo.s[j] = f2bf(ff[j] - bf2f(hb));
        }
      }
      aC = MFMA(Ahi.v, bhi.v, aC);
      aC = MFMA(Alo.v, bhi.v, aC);
      aC = MFMA(Ahi.v, blo.v, aC);
    }
    float bhv = bh[colH], bcv = bc[colH];
    float pp0[4][2];
    #pragma unroll
    for (int r = 0; r < 4; ++r) {
      float h0v = aH[r] + bhv;
      cst[r] = aC[r] + bcv;
      sh_h[0][(q * 4 + r) * STR + colH] = (__bf16)h0v;
      pp0[r][0] = h0v * wo0;
      pp0[r][1] = h0v * wo1;
    }
    #pragma unroll
    for (int r = 0; r < 4; ++r) {
      pp0[r][0] = row_reduce16(pp0[r][0]);
      pp0[r][1] = row_reduce16(pp0[r][1]);
    }
    if (c16 == 0) {
      #pragma unroll
      for (int r = 0; r < 4; ++r) {
        sh_pw0[w][(q * 4 + r) * 2 + 0] = pp0[r][0];
        sh_pw0[w][(q * 4 + r) * 2 + 1] = pp0[r][1];
      }
    }
  }
  __syncthreads();   // sA/sB reuse + pw0 visibility

  // ---- stage static_in = [ball(2), enc(128), pad] (stride 168) ----
  for (int e = tid; e < BB * 168; e += 512) {
    int row = e / 168, col = e - row * 168;
    float x = (col < 2) ? ball[(size_t)(rbase + row) * 2 + col]
            : (col < 130) ? enc[(size_t)(rbase + row) * 128 + (col - 2)] : 0.f;
    unsigned short hb = f2bf(x);
    sh_sA[row * 168 + col] = hb;
    sh_sB[row * 168 + col] = f2bf(x - bf2f(hb));
  }
  // virtual pred_{-1} = h0 @ Wo.T + bo
  if (tid < BB * 2) {
    float s = (tid & 1) ? bo1 : bo0;
    #pragma unroll
    for (int w2 = 0; w2 < 8; ++w2) s += sh_pw0[w2][tid];
    sh_p0[tid] = s;
  }
  __syncthreads();

  // ---- gate_static (3-product, K=160, SG-scaled) + biases -> LDS ----
  {
    f32x4 gacc[4] = {{0.f,0.f,0.f,0.f},{0.f,0.f,0.f,0.f},{0.f,0.f,0.f,0.f},{0.f,0.f,0.f,0.f}};
    #pragma unroll
    for (int kt = 0; kt < 5; ++kt) {
      frag_u Ahi, Alo;
      Ahi.u4 = *(const uint4*)&sh_sA[c16 * 168 + kt * 32 + q * 8];
      Alo.u4 = *(const uint4*)&sh_sB[c16 * 168 + kt * 32 + q * 8];
      #pragma unroll
      for (int g = 0; g < 4; ++g) {
        frag_u bhi, blo;
        #pragma unroll
        for (int j = 0; j < 8; ++j) {
          int kk = kt * 32 + q * 8 + j;
          float x = (kk < 130) ? SG[g] * W_ih[(size_t)(g * HDIM + colH) * 132 + 2 + kk] : 0.f;
          unsigned short hb = f2bf(x);
          bhi.s[j] = hb;
          blo.s[j] = f2bf(x - bf2f(hb));
        }
        gacc[g] = MFMA(Ahi.v, bhi.v, gacc[g]);
        gacc[g] = MFMA(Alo.v, bhi.v, gacc[g]);
        gacc[g] = MFMA(Ahi.v, blo.v, gacc[g]);
      }
    }
    #pragma unroll
    for (int g = 0; g < 4; ++g) {
      int colG = g * HDIM + colH;
      float bb = SG[g] * (b_ih[colG] + b_hh[colG] + bo0 * wp0[g] + bo1 * wp1[g]);
      #pragma unroll
      for (int r = 0; r < 4; ++r) gacc[g][r] += bb;
      sh_g4[g][tid] = gacc[g];          // per-lane private slot
    }
  }
  // scaled feedback weights for the t=0 correction (live only through body(0))
  float wps0[4], wps1[4];
  #pragma unroll
  for (int g = 0; g < 4; ++g) { wps0[g] = SG[g] * wp0[g]; wps1[g] = SG[g] * wp1[g]; }

  // ---- time loop: ONE barrier/step; gacc from LDS as MFMA C-seed ----
  auto body = [&](int t, int rbuf, bool first) {
    const int wbuf = rbuf ^ 1;

    const __bf16* hp = &sh_h[rbuf][c16 * STR];
    f32x4 acc[4];
    f32x4 accP = {0.f, 0.f, 0.f, 0.f};
    {
      frag_u A;
      A.u4 = *(const uint4*)(hp + q * 8);
      #pragma unroll
      for (int g = 0; g < 4; ++g)
        acc[g] = MFMA(A.v, Wf[g][0].v, sh_g4[g][tid]);
      if (!first && w == 7) {
        frag_u Bw; Bw.u4 = sh_wof[0][l];
        accP = MFMA(A.v, Bw.v, accP);
      }
    }
    #pragma unroll
    for (int kt = 1; kt < 4; ++kt) {
      frag_u A;
      A.u4 = *(const uint4*)(hp + kt * 32 + q * 8);
      #pragma unroll
      for (int g = 0; g < 4; ++g)
        acc[g] = MFMA(A.v, Wf[g][kt].v, acc[g]);
      if (!first && w == 7) {
        frag_u Bw; Bw.u4 = sh_wof[kt][l];
        accP = MFMA(A.v, Bw.v, accP);
      }
    }
    if (first) {  // prev0 = 0: remove folded pred_{-1} feedback (scaled units)
      #pragma unroll
      for (int r = 0; r < 4; ++r) {
        float2 p0r = *(const float2*)&sh_p0[(q * 4 + r) * 2];
        #pragma unroll
        for (int g = 0; g < 4; ++g)
          acc[g][r] -= p0r.x * wps0[g] + p0r.y * wps1[g];
      }
    }
    // store pred[t-1]
    if (!first && w == 7 && c16 < 2) {
      const float bov = c16 ? bo1 : bo0;
      #pragma unroll
      for (int r = 0; r < 4; ++r)
        outp[(size_t)(rbase + q * 4 + r) * (T_FRAMES * 2) + (t - 1) * 2 + c16] = accP[r] + bov;
    }

    // elementwise update: 7 trans/element, exp2-prescaled gates
    __bf16* hw = &sh_h[wbuf][colH];
    #pragma unroll
    for (int r = 0; r < 4; ++r) {
      float ei = EXP2(-acc[0][r]);              // e^{-i}
      float ef = EXP2(-acc[1][r]);              // e^{-f}
      float eg = EXP2(-acc[2][r]);              // e^{-2g}
      float eo = EXP2(-acc[3][r]);              // e^{-o}
      float t1 = (1.f + ei) * (1.f + eg);
      float pf = 1.f + ef;
      float num = cst[r] * t1 + (1.f - eg) * pf;
      float cv = num * RCP(t1 * pf);
      cst[r] = cv;
      float cc = fmaxf(cv, -15.f);              // only -inf side can overflow exp2
      float ec = EXP2(cc * (-2.f * 1.4426950408889634f));
      float hv = (1.f - ec) * RCP((1.f + eo) * (1.f + ec));
      hw[(q * 4 + r) * STR] = (__bf16)hv;
    }
    __syncthreads();
  };

  body(0, 0, true);    // reads h0 (buf0), writes buf1
  for (int tp = 0; tp < 63; ++tp) {
    body(2 * tp + 1, 1, false);
    body(2 * tp + 2, 0, false);
  }
  body(127, 1, false);   // stores pred[126]; final h_128 lands in buf 0

  // ---- epilogue: pred[127] from final h (buf 0), wave 7 ----
  if (w == 7) {
    const __bf16* hp = &sh_h[0][c16 * STR];
    f32x4 accP = {0.f, 0.f, 0.f, 0.f};
    #pragma unroll
    for (int kt = 0; kt < 4; ++kt) {
      frag_u A, Bw;
      A.u4 = *(const uint4*)(hp + kt * 32 + q * 8);
      Bw.u4 = sh_wof[kt][l];
      accP = MFMA(A.v, Bw.v, accP);
    }
    if (c16 < 2) {
      const float bov = c16 ? bo1 : bo0;
      #pragma unroll
      for (int r = 0; r < 4; ++r)
        outp[(size_t)(rbase + q * 4 + r) * (T_FRAMES * 2) + 127 * 2 + c16] = accP[r] + bov;
    }
  }
}

extern "C" void kernel_launch(void* const* d_in, const int* in_sizes, int n_in,
                              void* d_out, int out_size, void* d_ws, size_t ws_size,
                              hipStream_t stream) {
  (void)in_sizes; (void)n_in; (void)d_ws; (void)ws_size; (void)out_size;
  const float* ctx  = (const float*)d_in[0];
  const float* enc  = (const float*)d_in[1];
  const float* ball = (const float*)d_in[2];
  // d_in[3] = max_frames (always 128)
  const float* Wh   = (const float*)d_in[4];
  const float* bh   = (const float*)d_in[5];
  const float* Wc   = (const float*)d_in[6];
  const float* bc   = (const float*)d_in[7];
  const float* W_ih = (const float*)d_in[8];
  const float* W_hh = (const float*)d_in[9];
  const float* b_ih = (const float*)d_in[10];
  const float* b_hh = (const float*)d_in[11];
  const float* Wo   = (const float*)d_in[12];
  const float* bo   = (const float*)d_in[13];
  float* outp = (float*)d_out;

  dim3 grid(512), block(512);
  traj_lstm<<<grid, block, 0, stream>>>(ctx, enc, ball, Wh, bh, Wc, bc,
                                        W_ih, W_hh, b_ih, b_hh, Wo, bo, outp);
}

// Round 10
// 308.356 us; speedup vs baseline: 1.1549x; 1.1549x over previous
//
#include <hip/hip_runtime.h>
#include <hip/hip_bf16.h>

// TrajectoryDecoder: B=8192 LSTM, T=128, H=128, CTX=256, IN_DIM=132.
// R10 = R8's proven no-spill structure (BB=32, 1 block/CU, 2 row-tiles/wave,
// reg gate_static, MFMA C-seed, waves-6/7 MFMA pred) + R9's leaner
// elementwise (validated there, masked by spills):
//  - exp2 with log2e pre-folded into per-gate scaling SG={L,L,2L,L}
//  - 7 trans/element: common-denominator c-update, single fmax(cv,-15) guard
// R9 post-mortem: waves_per_eu(4) co-residency works (41% occ) but the
// compiler splits the unified file 64/64 and spills Wf -> scratch (190 MB).
// Co-residency axis parked; this is the consolidation round.

#define HDIM 128
#define CTX_DIM 256
#define T_FRAMES 128
#define BB 32     // batch rows per block
#define STR 136   // h row stride (elements); 272B rows keep 16B alignment

typedef __bf16 bf16x8 __attribute__((ext_vector_type(8)));
typedef float  f32x4  __attribute__((ext_vector_type(4)));

union frag_u {
  bf16x8 v;
  unsigned short s[8];
  uint4 u4;
};

#if __has_builtin(__builtin_amdgcn_exp2f)
#define EXP2(x) __builtin_amdgcn_exp2f(x)
#else
#define EXP2(x) __expf((x) * 0.6931471805599453f)
#endif
#define RCP(x) __builtin_amdgcn_rcpf(x)

__device__ __forceinline__ unsigned short f2bf(float x) {
  unsigned u = __builtin_bit_cast(unsigned, x);
  u += 0x7FFFu + ((u >> 16) & 1u);          // RNE to bf16
  return (unsigned short)(u >> 16);
}
__device__ __forceinline__ float bf2f(unsigned short h) {
  unsigned u = ((unsigned)h) << 16;
  return __builtin_bit_cast(float, u);
}
template<int CTRL>
__device__ __forceinline__ float dpp_mov(float x) {
  return __builtin_bit_cast(float,
    __builtin_amdgcn_mov_dpp(__builtin_bit_cast(int, x), CTRL, 0xF, 0xF, true));
}
// sum over the 16-lane row group (setup-only)
__device__ __forceinline__ float row_reduce16(float v) {
  v += dpp_mov<0xB1>(v);     // quad_perm xor1
  v += dpp_mov<0x4E>(v);     // quad_perm xor2
  v += dpp_mov<0x124>(v);    // row_ror:4
  v += dpp_mov<0x128>(v);    // row_ror:8
  return v;
}

#define MFMA(a, b, c) __builtin_amdgcn_mfma_f32_16x16x32_bf16((a), (b), (c), 0, 0, 0)

__global__ __launch_bounds__(512, 1) void traj_lstm(
    const float* __restrict__ ctx, const float* __restrict__ enc,
    const float* __restrict__ ball,
    const float* __restrict__ Wh, const float* __restrict__ bh,
    const float* __restrict__ Wc, const float* __restrict__ bc,
    const float* __restrict__ W_ih, const float* __restrict__ W_hh,
    const float* __restrict__ b_ih, const float* __restrict__ b_hh,
    const float* __restrict__ Wo, const float* __restrict__ bo,
    float* __restrict__ outp)
{
  __shared__ __align__(16) __bf16 sh_h[2][BB * STR];          // h double buffer (17.4 KB)
  __shared__ __align__(16) unsigned short sh_sA[BB * 264];    // setup staging hi (16.9 KB)
  __shared__ __align__(16) unsigned short sh_sB[BB * 264];    // setup staging lo (16.9 KB)
  __shared__ float sh_pw0[8][BB * 2];     // setup pred partials (2 KB)
  __shared__ float sh_p0[BB * 2];         // virtual pred_{-1} for t=0 correction

  const int tid  = threadIdx.x;
  const int w    = tid >> 6;
  const int l    = tid & 63;
  const int q    = l >> 4;
  const int c16  = l & 15;
  const int colH = w * 16 + c16;
  const int rbase = blockIdx.x * BB;

  const float Lc = 1.4426950408889634f;          // log2(e)
  const float SG[4] = {Lc, Lc, 2.f * Lc, Lc};    // i, f, g, o exp2 prescales
  const float bo0 = bo[0], bo1 = bo[1];
  const float wo0 = Wo[colH], wo1 = Wo[HDIM + colH];

  // feedback weights per gate (W_prev columns)
  float wp0[4], wp1[4];
  #pragma unroll
  for (int g = 0; g < 4; ++g) {
    wp0[g] = W_ih[(size_t)(g * HDIM + colH) * 132 + 0];
    wp1[g] = W_ih[(size_t)(g * HDIM + colH) * 132 + 1];
  }

  // ---- persistent W_eff fragments: SG[g]*(W_hh + wp0*Wo0 + wp1*Wo1) ----
  frag_u Wf[4][4];                  // [gate][ktile]
  #pragma unroll
  for (int kt = 0; kt < 4; ++kt) {
    const float* w0p = Wo + kt * 32 + q * 8;
    const float* w1p = Wo + HDIM + kt * 32 + q * 8;
    float4 a0 = *(const float4*)w0p, a1 = *(const float4*)(w0p + 4);
    float4 b0 = *(const float4*)w1p, b1 = *(const float4*)(w1p + 4);
    float wo0v[8] = {a0.x, a0.y, a0.z, a0.w, a1.x, a1.y, a1.z, a1.w};
    float wo1v[8] = {b0.x, b0.y, b0.z, b0.w, b1.x, b1.y, b1.z, b1.w};
    #pragma unroll
    for (int g = 0; g < 4; ++g) {
      const float* wr = W_hh + (size_t)(g * HDIM + colH) * HDIM + kt * 32 + q * 8;
      float4 f0 = *(const float4*)wr;
      float4 f1 = *(const float4*)(wr + 4);
      float ff[8] = {f0.x, f0.y, f0.z, f0.w, f1.x, f1.y, f1.z, f1.w};
      #pragma unroll
      for (int j = 0; j < 8; ++j)
        Wf[g][kt].s[j] = f2bf(SG[g] * (ff[j] + wp0[g] * wo0v[j] + wp1[g] * wo1v[j]));
    }
  }

  // ---- Wo B-fragments for the in-loop pred MFMA (used by waves 6/7) ----
  frag_u WoF[4];
  #pragma unroll
  for (int kt = 0; kt < 4; ++kt) {
    #pragma unroll
    for (int j = 0; j < 8; ++j) {
      float x = (c16 < 2) ? Wo[c16 * HDIM + kt * 32 + q * 8 + j] : 0.f;
      WoF[kt].s[j] = f2bf(x);
    }
  }

  // ---- stage context rows (32 rows, hi/lo bf16, stride 264) ----
  for (int e = tid; e < BB * 256; e += 512) {
    int row = e >> 8, col = e & 255;
    float x = ctx[(size_t)(rbase + row) * CTX_DIM + col];
    unsigned short hb = f2bf(x);
    sh_sA[row * 264 + col] = hb;
    sh_sB[row * 264 + col] = f2bf(x - bf2f(hb));
  }
  __syncthreads();

  // ---- h0/c0 = ctx @ Wh.T/Wc.T + bias (3-product split, K=256, 2 row-tiles) ----
  float cst[8];   // [rt*4 + r]  (raw units)
  {
    f32x4 aH[2] = {{0.f,0.f,0.f,0.f},{0.f,0.f,0.f,0.f}};
    f32x4 aC[2] = {{0.f,0.f,0.f,0.f},{0.f,0.f,0.f,0.f}};
    #pragma unroll
    for (int kt = 0; kt < 8; ++kt) {
      frag_u Ahi[2], Alo[2];
      #pragma unroll
      for (int rt = 0; rt < 2; ++rt) {
        Ahi[rt].u4 = *(const uint4*)&sh_sA[(rt * 16 + c16) * 264 + kt * 32 + q * 8];
        Alo[rt].u4 = *(const uint4*)&sh_sB[(rt * 16 + c16) * 264 + kt * 32 + q * 8];
      }
      frag_u bhi, blo;
      {
        const float* wr = Wh + (size_t)colH * CTX_DIM + kt * 32 + q * 8;
        float4 f0 = *(const float4*)wr;
        float4 f1 = *(const float4*)(wr + 4);
        float ff[8] = {f0.x, f0.y, f0.z, f0.w, f1.x, f1.y, f1.z, f1.w};
        #pragma unroll
        for (int j = 0; j < 8; ++j) {
          unsigned short hb = f2bf(ff[j]);
          bhi.s[j] = hb;
          blo.s[j] = f2bf(ff[j] - bf2f(hb));
        }
      }
      #pragma unroll
      for (int rt = 0; rt < 2; ++rt) {
        aH[rt] = MFMA(Ahi[rt].v, bhi.v, aH[rt]);
        aH[rt] = MFMA(Alo[rt].v, bhi.v, aH[rt]);
        aH[rt] = MFMA(Ahi[rt].v, blo.v, aH[rt]);
      }
      {
        const float* wr = Wc + (size_t)colH * CTX_DIM + kt * 32 + q * 8;
        float4 f0 = *(const float4*)wr;
        float4 f1 = *(const float4*)(wr + 4);
        float ff[8] = {f0.x, f0.y, f0.z, f0.w, f1.x, f1.y, f1.z, f1.w};
        #pragma unroll
        for (int j = 0; j < 8; ++j) {
          unsigned short hb = f2bf(ff[j]);
          bhi.s[j] = hb;
          blo.s[j] = f2bf(ff[j] - bf2f(hb));
        }
      }
      #pragma unroll
      for (int rt = 0; rt < 2; ++rt) {
        aC[rt] = MFMA(Ahi[rt].v, bhi.v, aC[rt]);
        aC[rt] = MFMA(Alo[rt].v, bhi.v, aC[rt]);
        aC[rt] = MFMA(Ahi[rt].v, blo.v, aC[rt]);
      }
    }
    float bhv = bh[colH], bcv = bc[colH];
    float pp0[8][2];
    #pragma unroll
    for (int rt = 0; rt < 2; ++rt) {
      #pragma unroll
      for (int r = 0; r < 4; ++r) {
        float h0v = aH[rt][r] + bhv;
        cst[rt * 4 + r] = aC[rt][r] + bcv;
        sh_h[0][(rt * 16 + q * 4 + r) * STR + colH] = (__bf16)h0v;
        pp0[rt * 4 + r][0] = h0v * wo0;
        pp0[rt * 4 + r][1] = h0v * wo1;
      }
    }
    #pragma unroll
    for (int m = 0; m < 8; ++m) {
      pp0[m][0] = row_reduce16(pp0[m][0]);
      pp0[m][1] = row_reduce16(pp0[m][1]);
    }
    if (c16 == 0) {
      #pragma unroll
      for (int rt = 0; rt < 2; ++rt)
        #pragma unroll
        for (int r = 0; r < 4; ++r) {
          sh_pw0[w][(rt * 16 + q * 4 + r) * 2 + 0] = pp0[rt * 4 + r][0];
          sh_pw0[w][(rt * 16 + q * 4 + r) * 2 + 1] = pp0[rt * 4 + r][1];
        }
    }
  }
  __syncthreads();   // sA/sB reuse + pw0 visibility

  // ---- stage static_in = [ball(2), enc(128), pad] (32 rows, stride 168) ----
  for (int e = tid; e < BB * 168; e += 512) {
    int row = e / 168, col = e - row * 168;
    float x = (col < 2) ? ball[(size_t)(rbase + row) * 2 + col]
            : (col < 130) ? enc[(size_t)(rbase + row) * 128 + (col - 2)] : 0.f;
    unsigned short hb = f2bf(x);
    sh_sA[row * 168 + col] = hb;
    sh_sB[row * 168 + col] = f2bf(x - bf2f(hb));
  }
  // virtual pred_{-1} = h0 @ Wo.T + bo (t=0 feedback correction)
  if (tid < BB * 2) {
    float s = (tid & 1) ? bo1 : bo0;
    #pragma unroll
    for (int w2 = 0; w2 < 8; ++w2) s += sh_pw0[w2][tid];
    sh_p0[tid] = s;
  }
  __syncthreads();

  // ---- gate_static (3-product, K=160, SG-scaled) + biases, in REGISTERS ----
  f32x4 gacc[2][4] = {{{0.f,0.f,0.f,0.f},{0.f,0.f,0.f,0.f},{0.f,0.f,0.f,0.f},{0.f,0.f,0.f,0.f}},
                      {{0.f,0.f,0.f,0.f},{0.f,0.f,0.f,0.f},{0.f,0.f,0.f,0.f},{0.f,0.f,0.f,0.f}}};
  #pragma unroll
  for (int kt = 0; kt < 5; ++kt) {
    frag_u Ahi[2], Alo[2];
    #pragma unroll
    for (int rt = 0; rt < 2; ++rt) {
      Ahi[rt].u4 = *(const uint4*)&sh_sA[(rt * 16 + c16) * 168 + kt * 32 + q * 8];
      Alo[rt].u4 = *(const uint4*)&sh_sB[(rt * 16 + c16) * 168 + kt * 32 + q * 8];
    }
    #pragma unroll
    for (int g = 0; g < 4; ++g) {
      frag_u bhi, blo;
      #pragma unroll
      for (int j = 0; j < 8; ++j) {
        int kk = kt * 32 + q * 8 + j;
        float x = (kk < 130) ? SG[g] * W_ih[(size_t)(g * HDIM + colH) * 132 + 2 + kk] : 0.f;
        unsigned short hb = f2bf(x);
        bhi.s[j] = hb;
        blo.s[j] = f2bf(x - bf2f(hb));
      }
      #pragma unroll
      for (int rt = 0; rt < 2; ++rt) {
        gacc[rt][g] = MFMA(Ahi[rt].v, bhi.v, gacc[rt][g]);
        gacc[rt][g] = MFMA(Alo[rt].v, bhi.v, gacc[rt][g]);
        gacc[rt][g] = MFMA(Ahi[rt].v, blo.v, gacc[rt][g]);
      }
    }
  }
  // scaled feedback weights (t=0 correction operates in scaled units)
  float wps0[4], wps1[4];
  #pragma unroll
  for (int g = 0; g < 4; ++g) {
    int colG = g * HDIM + colH;
    float bb = SG[g] * (b_ih[colG] + b_hh[colG] + bo0 * wp0[g] + bo1 * wp1[g]);
    #pragma unroll
    for (int rt = 0; rt < 2; ++rt)
      #pragma unroll
      for (int r = 0; r < 4; ++r) gacc[rt][g][r] += bb;
    wps0[g] = SG[g] * wp0[g];
    wps1[g] = SG[g] * wp1[g];
  }

  // ---- time loop: ONE barrier per step; pred via MFMA on waves 6/7 ----
  auto body = [&](int t, int rbuf, bool first) {
    const int wbuf = rbuf ^ 1;

    const __bf16* hp0 = &sh_h[rbuf][c16 * STR];
    const __bf16* hp1 = &sh_h[rbuf][(16 + c16) * STR];
    f32x4 acc[2][4];
    f32x4 accP = {0.f, 0.f, 0.f, 0.f};
    {
      frag_u A0, A1;
      A0.u4 = *(const uint4*)(hp0 + q * 8);
      A1.u4 = *(const uint4*)(hp1 + q * 8);
      #pragma unroll
      for (int g = 0; g < 4; ++g) {
        acc[0][g] = MFMA(A0.v, Wf[g][0].v, gacc[0][g]);
        acc[1][g] = MFMA(A1.v, Wf[g][0].v, gacc[1][g]);
      }
      if (!first && w >= 6)
        accP = MFMA((w == 6 ? A0.v : A1.v), WoF[0].v, accP);
    }
    #pragma unroll
    for (int kt = 1; kt < 4; ++kt) {
      frag_u A0, A1;
      A0.u4 = *(const uint4*)(hp0 + kt * 32 + q * 8);
      A1.u4 = *(const uint4*)(hp1 + kt * 32 + q * 8);
      #pragma unroll
      for (int g = 0; g < 4; ++g) {
        acc[0][g] = MFMA(A0.v, Wf[g][kt].v, acc[0][g]);
        acc[1][g] = MFMA(A1.v, Wf[g][kt].v, acc[1][g]);
      }
      if (!first && w >= 6)
        accP = MFMA((w == 6 ? A0.v : A1.v), WoF[kt].v, accP);
    }
    if (first) {  // prev0 = 0: remove the folded pred_{-1} feedback (scaled)
      #pragma unroll
      for (int rt = 0; rt < 2; ++rt)
        #pragma unroll
        for (int r = 0; r < 4; ++r) {
          float2 p0r = *(const float2*)&sh_p0[(rt * 16 + q * 4 + r) * 2];
          #pragma unroll
          for (int g = 0; g < 4; ++g)
            acc[rt][g][r] -= p0r.x * wps0[g] + p0r.y * wps1[g];
        }
    }
    // store pred[t-1] (complete in-wave: D[m=q*4+r][n=c16], n<2 are real dims)
    if (!first && w >= 6 && c16 < 2) {
      const int m0 = (w - 6) * 16 + q * 4;
      const float bov = c16 ? bo1 : bo0;
      #pragma unroll
      for (int r = 0; r < 4; ++r)
        outp[(size_t)(rbase + m0 + r) * (T_FRAMES * 2) + (t - 1) * 2 + c16] = accP[r] + bov;
    }

    // elementwise update: 7 trans/element, exp2-prescaled gates
    #pragma unroll
    for (int rt = 0; rt < 2; ++rt) {
      __bf16* hw = &sh_h[wbuf][rt * 16 * STR + colH];
      #pragma unroll
      for (int r = 0; r < 4; ++r) {
        float ei = EXP2(-acc[rt][0][r]);          // e^{-i}
        float ef = EXP2(-acc[rt][1][r]);          // e^{-f}
        float eg = EXP2(-acc[rt][2][r]);          // e^{-2g}
        float eo = EXP2(-acc[rt][3][r]);          // e^{-o}
        float t1 = (1.f + ei) * (1.f + eg);
        float pf = 1.f + ef;
        float num = cst[rt * 4 + r] * t1 + (1.f - eg) * pf;
        float cv = num * RCP(t1 * pf);
        cst[rt * 4 + r] = cv;
        float cc = fmaxf(cv, -15.f);              // only -inf side can overflow
        float ec = EXP2(cc * (-2.f * 1.4426950408889634f));
        float hv = (1.f - ec) * RCP((1.f + eo) * (1.f + ec));
        hw[(q * 4 + r) * STR] = (__bf16)hv;
      }
    }
    __syncthreads();
  };

  body(0, 0, true);    // reads h0 (buf0), writes buf1
  for (int tp = 0; tp < 63; ++tp) {
    body(2 * tp + 1, 1, false);
    body(2 * tp + 2, 0, false);
  }
  body(127, 1, false);   // stores pred[126]; final h_128 lands in buf 0

  // ---- epilogue: pred[127] from final h (buf 0), waves 6/7 ----
  if (w >= 6) {
    const __bf16* hp = &sh_h[0][((w - 6) * 16 + c16) * STR];
    f32x4 accP = {0.f, 0.f, 0.f, 0.f};
    #pragma unroll
    for (int kt = 0; kt < 4; ++kt) {
      frag_u A;
      A.u4 = *(const uint4*)(hp + kt * 32 + q * 8);
      accP = MFMA(A.v, WoF[kt].v, accP);
    }
    if (c16 < 2) {
      const int m0 = (w - 6) * 16 + q * 4;
      const float bov = c16 ? bo1 : bo0;
      #pragma unroll
      for (int r = 0; r < 4; ++r)
        outp[(size_t)(rbase + m0 + r) * (T_FRAMES * 2) + 127 * 2 + c16] = accP[r] + bov;
    }
  }
}

extern "C" void kernel_launch(void* const* d_in, const int* in_sizes, int n_in,
                              void* d_out, int out_size, void* d_ws, size_t ws_size,
                              hipStream_t stream) {
  (void)in_sizes; (void)n_in; (void)d_ws; (void)ws_size; (void)out_size;
  const float* ctx  = (const float*)d_in[0];
  const float* enc  = (const float*)d_in[1];
  const float* ball = (const float*)d_in[2];
  // d_in[3] = max_frames (always 128)
  const float* Wh   = (const float*)d_in[4];
  const float* bh   = (const float*)d_in[5];
  const float* Wc   = (const float*)d_in[6];
  const float* bc   = (const float*)d_in[7];
  const float* W_ih = (const float*)d_in[8];
  const float* W_hh = (const float*)d_in[9];
  const float* b_ih = (const float*)d_in[10];
  const float* b_hh = (const float*)d_in[11];
  const float* Wo   = (const float*)d_in[12];
  const float* bo   = (const float*)d_in[13];
  float* outp = (float*)d_out;

  dim3 grid(256), block(512);
  traj_lstm<<<grid, block, 0, stream>>>(ctx, enc, ball, Wh, bh, Wc, bc,
                                        W_ih, W_hh, b_ih, b_hh, Wo, bo, outp);
}